// Round 9
// baseline (145.532 us; speedup 1.0000x reference)
//
#include <hip/hip_runtime.h>

#define B_ 2
#define N_ 4096
#define M_ 2048
#define D_ 256
#define H_ 8
#define DH_ 32
#define ROWS_ (B_*N_)
#define KVROWS_ (B_*M_)
// SCALE * log2(e): q pre-scaled so softmax = exp2
#define PRE_ (0.17677669529663687f * 1.4426950408889634f)
#define CBASE_ 32.0f

typedef __attribute__((ext_vector_type(8))) short short8_t;
typedef __attribute__((ext_vector_type(4))) float float4_t;

#if defined(__has_builtin)
# if __has_builtin(__builtin_amdgcn_exp2f)
#  define EXP2F(x) __builtin_amdgcn_exp2f(x)
# else
#  define EXP2F(x) exp2f(x)
# endif
#else
# define EXP2F(x) exp2f(x)
#endif

// RTNE round-to-bf16 helper: rounded 32-bit word (bf16 in high half)
__device__ __forceinline__ unsigned int rne_u(float f) {
    union { float f; unsigned int u; } c;
    c.f = f;
    return c.u + 0x7FFFu + ((c.u >> 16) & 1u);
}

__device__ __forceinline__ unsigned short f2us(float f) {
    return (unsigned short)(rne_u(f) >> 16);
}

// pack two RTNE bf16: low16 = a, high16 = b  (single v_perm_b32 combine)
__device__ __forceinline__ unsigned int pack2rn(float a, float b) {
    return __builtin_amdgcn_perm(rne_u(b), rne_u(a), 0x07060302u);
}

// truncation pack (P tiles only; <=2^-8 rel err) — single v_perm_b32
__device__ __forceinline__ unsigned int pack2tr(float a, float b) {
    union { float f; unsigned int u; } x, y;
    x.f = a; y.f = b;
    return __builtin_amdgcn_perm(y.u, x.u, 0x07060302u);
}

__device__ __forceinline__ short8_t cvt8(float4 a, float4 b) {
    union { unsigned int u[4]; short8_t s; } c;
    c.u[0] = pack2rn(a.x, a.y);
    c.u[1] = pack2rn(a.z, a.w);
    c.u[2] = pack2rn(b.x, b.y);
    c.u[3] = pack2rn(b.z, b.w);
    return c.s;
}

// bijective XCD-aware block-id swizzle (valid when nwg % 8 == 0)
__device__ __forceinline__ int xcd_swz(int bid, int nwg) {
    const int cpx = nwg >> 3;
    return (bid & 7) * cpx + (bid >> 3);
}

// ---------------------------------------------------------------------------
// Stage NCOL x K fp32 weight block (source row stride LDSRC, col offset kof)
// into XOR-swizzled bf16 LDS.
// ---------------------------------------------------------------------------
template<int K, int NCOL, int LDSRC>
__device__ __forceinline__ void stageB2(const float* __restrict__ W, int col0, int kof,
                                        unsigned short* __restrict__ Bs, int tid)
{
    const int n = tid & (NCOL - 1), g = tid / NCOL;
    const int GROUPS = 256 / NCOL;
    const int CPT = (K / 8) / GROUPS;
    const float* src = W + (size_t)(col0 + n) * LDSRC + kof + g * (K / GROUPS);
#pragma unroll
    for (int ci = 0; ci < CPT; ci++) {
        int logc = g * CPT + ci;
        int phys = logc ^ (n & 7);
        short8_t v = cvt8(*(const float4*)(src + ci * 8), *(const float4*)(src + ci * 8 + 4));
        *(short8_t*)(Bs + (size_t)n * K + phys * 8) = v;
    }
}

template<int K>
__device__ __forceinline__ short8_t readB(const unsigned short* __restrict__ Bs,
                                          int c, int l16, int quad, int k0)
{
    int phys = ((k0 >> 3) + quad) ^ (l16 & 7);
    return *(const short8_t*)(Bs + (size_t)(16 * c + l16) * K + phys * 8);
}

// ---------------------------------------------------------------------------
// Proj v5: rank-4 K-fold.
// blocks [0,512): tile 64 rows x 64 cols (2 heads), K or V.
//   V-blocks: v = voxel@Wv.T -> vt_g (transposed)       [unchanged]
//   K-blocks: compute local Wqc slice (64 cols x 4, f32, from Wq/Wp/bp/bq),
//     k-GEMM acc (f32), fold kq[m,h,j] = sum_d Wqc[d,j]*(acc_d + bk_d) via
//     cross-lane reduce, write ONLY kq_g [b][h][m][4] bf16 (256 KB total).
//     k_g (8 MB) is gone: attention scores are rank-4 (S = pe . kq).
// block 512: Wfc[256][4] = (Wf1@Wp | Wf1@bp+bf)
// ---------------------------------------------------------------------------
__global__ __launch_bounds__(256) void g_projkv5(
    const float* __restrict__ voxel,
    const float* __restrict__ Wp, const float* __restrict__ bp,
    const float* __restrict__ Wq, const float* __restrict__ bq,
    const float* __restrict__ Wk, const float* __restrict__ bk,
    const float* __restrict__ Wv, const float* __restrict__ bv,
    const float* __restrict__ Wf, const float* __restrict__ bfb,
    unsigned short* __restrict__ kq_g, unsigned short* __restrict__ vt_g,
    float* __restrict__ Wfc)
{
    const int tid = threadIdx.x;
    const int wave = tid >> 6, lane = tid & 63, quad = lane >> 4, l16 = lane & 15;

    __shared__ unsigned short Bs[64 * 256];   // 32 KB
    __shared__ float Wqc_l[64 * 4];           //  1 KB

    const int bid = (int)blockIdx.x;
    if (bid < 512) {
        const int lbid = xcd_swz(bid, 512);
        const int row0 = (lbid >> 3) * 64;
        const int sub  = lbid & 7;
        const int col0 = (sub >> 1) * 64;
        const bool isV = sub & 1;

        if (!isV) {
            // ---- local Wqc slice (cols col0..col0+63), f32-exact ----
            float* wps = (float*)Bs;            // [256][4] Wp|bp (4 KB)
            float* P4  = (float*)Bs + 1024;     // [64][4] partial float4 (4 KB)
            *(float4*)(wps + tid * 4) = make_float4(Wp[tid * 3 + 0], Wp[tid * 3 + 1],
                                                    Wp[tid * 3 + 2], bp[tid]);
            __syncthreads();
            {
                const int cc = tid >> 2, part = tid & 3;
                const float* wrow = Wq + (size_t)(col0 + cc) * 256 + part * 64;
                const float* wpp = wps + part * 256;
                float a0 = 0.f, a1 = 0.f, a2 = 0.f, ab = 0.f;
#pragma unroll 4
                for (int e = 0; e < 64; e++) {
                    float wv = wrow[e];
                    float4 aa = *(const float4*)(wpp + e * 4);
                    a0 += wv * aa.x; a1 += wv * aa.y; a2 += wv * aa.z; ab += wv * aa.w;
                }
                *(float4*)(P4 + (size_t)tid * 4) = make_float4(a0, a1, a2, ab);
            }
            __syncthreads();
            if (tid < 64) {
                float4 s0 = *(const float4*)(P4 + (tid * 4 + 0) * 4);
                float4 s1 = *(const float4*)(P4 + (tid * 4 + 1) * 4);
                float4 s2 = *(const float4*)(P4 + (tid * 4 + 2) * 4);
                float4 s3 = *(const float4*)(P4 + (tid * 4 + 3) * 4);
                float a0 = (s0.x + s1.x) + (s2.x + s3.x);
                float a1 = (s0.y + s1.y) + (s2.y + s3.y);
                float a2 = (s0.z + s1.z) + (s2.z + s3.z);
                float ab = (s0.w + s1.w) + (s2.w + s3.w);
                *(float4*)(Wqc_l + tid * 4) =
                    make_float4(a0 * PRE_, a1 * PRE_, a2 * PRE_,
                                (ab + bq[col0 + tid]) * PRE_);
            }
            __syncthreads();    // Wqc_l done; Bs free for weight staging
        }

        stageB2<256, 64, 256>(isV ? Wv : Wk, col0, 0, Bs, tid);

        const float* arow = voxel + (size_t)(row0 + wave * 16 + l16) * D_;
        short8_t af[8];
#pragma unroll
        for (int i = 0; i < 8; i++)
            af[i] = cvt8(*(const float4*)(arow + i * 32 + quad * 8),
                         *(const float4*)(arow + i * 32 + quad * 8 + 4));

        float4_t acc[4];
#pragma unroll
        for (int c = 0; c < 4; c++) acc[c] = (float4_t){0.f, 0.f, 0.f, 0.f};
        __syncthreads();
#pragma unroll
        for (int i = 0; i < 8; i++)
#pragma unroll
            for (int c = 0; c < 4; c++)
                acc[c] = __builtin_amdgcn_mfma_f32_16x16x32_bf16(af[i], readB<256>(Bs, c, l16, quad, i * 32), acc[c], 0, 0, 0);

        if (isV) {
            const int b = row0 / M_;
            const int m0 = row0 - b * M_ + wave * 16 + quad * 4;
#pragma unroll
            for (int c = 0; c < 4; c++) {
                int col = col0 + 16 * c + l16;
                float bbv = bv[col];
                int h = col >> 5, dh = col & 31;
                unsigned int u0 = pack2rn(acc[c][0] + bbv, acc[c][1] + bbv);
                unsigned int u1 = pack2rn(acc[c][2] + bbv, acc[c][3] + bbv);
                *(uint2*)(vt_g + (size_t)((b * H_ + h) * DH_ + dh) * M_ + m0) = make_uint2(u0, u1);
            }
        } else {
            // ---- fold acc -> kq (heads hA = col0/32, hB = hA+1) ----
            float bkv[4];
#pragma unroll
            for (int c = 0; c < 4; c++) bkv[c] = bk[col0 + 16 * c + l16];
            float4 wq0 = *(const float4*)(Wqc_l + l16 * 4);
            float4 wq1 = *(const float4*)(Wqc_l + (16 + l16) * 4);
            float4 wq2 = *(const float4*)(Wqc_l + (32 + l16) * 4);
            float4 wq3 = *(const float4*)(Wqc_l + (48 + l16) * 4);
            const float* q0 = (const float*)&wq0;
            const float* q1 = (const float*)&wq1;
            const float* q2 = (const float*)&wq2;
            const float* q3 = (const float*)&wq3;
            float pA[4][4], pB[4][4];
#pragma unroll
            for (int r = 0; r < 4; r++) {
                float kA0 = acc[0][r] + bkv[0], kA1 = acc[1][r] + bkv[1];
                float kB0 = acc[2][r] + bkv[2], kB1 = acc[3][r] + bkv[3];
#pragma unroll
                for (int j = 0; j < 4; j++) {
                    pA[r][j] = kA0 * q0[j] + kA1 * q1[j];
                    pB[r][j] = kB0 * q2[j] + kB1 * q3[j];
                }
            }
#pragma unroll
            for (int m = 1; m < 16; m <<= 1)
#pragma unroll
                for (int r = 0; r < 4; r++)
#pragma unroll
                    for (int j = 0; j < 4; j++) {
                        pA[r][j] += __shfl_xor(pA[r][j], m);
                        pB[r][j] += __shfl_xor(pB[r][j], m);
                    }
            if (l16 == 0) {
                const int b = row0 >> 11;
                const int m0 = (row0 & (M_ - 1)) + wave * 16 + quad * 4;
                const int hA = col0 >> 5;
#pragma unroll
                for (int r = 0; r < 4; r++) {
                    unsigned int u0 = pack2rn(pA[r][0], pA[r][1]);
                    unsigned int u1 = pack2rn(pA[r][2], pA[r][3]);
                    *(uint2*)(kq_g + ((size_t)(b * H_ + hA) * M_ + m0 + r) * 4) = make_uint2(u0, u1);
                    unsigned int u2 = pack2rn(pB[r][0], pB[r][1]);
                    unsigned int u3 = pack2rn(pB[r][2], pB[r][3]);
                    *(uint2*)(kq_g + ((size_t)(b * H_ + hA + 1) * M_ + m0 + r) * 4) = make_uint2(u2, u3);
                }
            }
        }
    } else {
        // ---- prep: Wfc fold (f32 exact) ----
        float* wps = (float*)Bs;
        *(float4*)(wps + tid * 4) = make_float4(Wp[tid * 3 + 0], Wp[tid * 3 + 1],
                                                Wp[tid * 3 + 2], bp[tid]);
        __syncthreads();
        const int col = tid;
        const float* wrow = Wf + (size_t)col * 512;
        float a0 = 0.f, a1 = 0.f, a2 = 0.f, ab = 0.f;
#pragma unroll 4
        for (int d = 0; d < 256; d += 4) {
            float4 wv = *(const float4*)(wrow + d);
            float4 w0 = *(const float4*)(wps + (d + 0) * 4);
            float4 w1 = *(const float4*)(wps + (d + 1) * 4);
            float4 w2 = *(const float4*)(wps + (d + 2) * 4);
            float4 w3 = *(const float4*)(wps + (d + 3) * 4);
            a0 += wv.x * w0.x + wv.y * w1.x + wv.z * w2.x + wv.w * w3.x;
            a1 += wv.x * w0.y + wv.y * w1.y + wv.z * w2.y + wv.w * w3.y;
            a2 += wv.x * w0.z + wv.y * w1.z + wv.z * w2.z + wv.w * w3.z;
            ab += wv.x * w0.w + wv.y * w1.w + wv.z * w2.w + wv.w * w3.w;
        }
        *(float4*)(Wfc + (size_t)col * 4) = make_float4(a0, a1, a2, ab + bfb[col]);
    }
}

// ---------------------------------------------------------------------------
// MFMA flash attention v12: rank-4 scores.
// S[kv][q] = pe[q] . kq[kv]  (pe = (p0,p1,p2,1) bf16, kq bf16, MFMA K=32
// with 28 zero-padded slots via lane masks -> same 4 QK MFMAs/step, same
// g_t output permutation -> P lands in PV B-fragment order).
// kq for the whole head (16 KB) staged into LDS ONCE -> no K double-buffer,
// LDS 34 KB -> 4 blocks/CU target (launch_bounds(512,8), VGPR<=64).
// V: 4-buffer, 1 barrier / 2 steps; staging spread over all 512 threads
// (1 load + 1 ds_write per thread per 2 steps).
// ---------------------------------------------------------------------------
__global__ __launch_bounds__(512, 8) void k_attn12(
    const float* __restrict__ points,
    const unsigned short* __restrict__ kq_g,
    const unsigned short* __restrict__ vt_g,
    unsigned short* __restrict__ att_g)
{
    const int tid = threadIdx.x;
    const int w = tid >> 6, lane = tid & 63, quad = lane >> 4, l16 = lane & 15;
    const int lbid = xcd_swz((int)blockIdx.x, 512);
    const int nt = lbid & 31;             // N/128
    const int bh = lbid >> 5;             // b*8+h
    const int b = bh >> 3;
    const int n0 = nt * 128 + w * 16;

    __shared__ unsigned short SL[17408];  // kqL 8192 + Vt 4x32x72 = 34 KB
    unsigned short* kqL = SL;
    unsigned short* Vt  = SL + 8192;

    // ---- stage kq for this head: 8192 shorts, 16 per thread ----
    {
        const unsigned short* ksrc = kq_g + (size_t)bh * (M_ * 4);
        const int off = tid * 16;
        *(short8_t*)(kqL + off)     = *(const short8_t*)(ksrc + off);
        *(short8_t*)(kqL + off + 8) = *(const short8_t*)(ksrc + off + 8);
    }

    // ---- V staging role: all 512 threads, 1 chunk / 2 steps ----
    const unsigned short* vbase = vt_g + (size_t)bh * DH_ * M_;
    const int vr = (tid & 255) >> 3, vc = tid & 7;
    const int half = tid >> 8;
    unsigned short* vdst = Vt + vr * 72 + vc * 8;
    const unsigned short* gqv = vbase + (size_t)vr * M_ + vc * 8;
    *(short8_t*)(vdst + half * 2304) = *(const short8_t*)(gqv + half * 64);
    gqv += (2 + half) * 64;

    // ---- pe fragment (B-operand): quad0 = (p0,p1,p2,1), rest zero ----
    const size_t qrow = (size_t)(b * N_ + n0 + l16);
    const float p0 = points[qrow * 3 + 0];
    const float p1 = points[qrow * 3 + 1];
    const float p2 = points[qrow * 3 + 2];
    const unsigned int um = (quad == 0) ? 0xFFFFFFFFu : 0u;
    union { unsigned int u[4]; short8_t s; } qfu;
    qfu.u[0] = pack2rn(p0, p1) & um;
    qfu.u[1] = pack2rn(p2, 1.0f) & um;
    qfu.u[2] = 0u; qfu.u[3] = 0u;
    const short8_t qf = qfu.s;

    short8_t ones;
#pragma unroll
    for (int j = 0; j < 8; j++) ones[j] = (short)0x3F80;

    // per-lane kq LDS base: kv = 8*(l16>>2) + (l16&3)  (g_t row permutation)
    const unsigned short* kqp = kqL + (8 * (l16 >> 2) + (l16 & 3)) * 4;

    float4_t od0 = {0.f, 0.f, 0.f, 0.f};
    float4_t od1 = {0.f, 0.f, 0.f, 0.f};
    float4_t lacc = {0.f, 0.f, 0.f, 0.f};
    const float4_t zc = {-CBASE_, -CBASE_, -CBASE_, -CBASE_};

    __syncthreads();

#define STEPC(VB_, KQP_)                                                        \
    do {                                                                        \
        float4_t st[4];                                                         \
        _Pragma("unroll")                                                       \
        for (int t = 0; t < 4; t++) {                                           \
            uint2 kv2 = *(const uint2*)((KQP_) + (t & 1) * 16 + (t >> 1) * 128);\
            union { unsigned int u[4]; short8_t s; } afu;                       \
            afu.u[0] = kv2.x & um; afu.u[1] = kv2.y & um;                       \
            afu.u[2] = 0u; afu.u[3] = 0u;                                       \
            st[t] = __builtin_amdgcn_mfma_f32_16x16x32_bf16(afu.s, qf, zc, 0, 0, 0); \
        }                                                                       \
        unsigned int uu[4][2];                                                  \
        _Pragma("unroll")                                                       \
        for (int t = 0; t < 4; t++) {                                           \
            float e0 = EXP2F(st[t][0]);                                         \
            float e1 = EXP2F(st[t][1]);                                         \
            float e2 = EXP2F(st[t][2]);                                         \
            float e3 = EXP2F(st[t][3]);                                         \
            uu[t][0] = pack2tr(e0, e1);                                         \
            uu[t][1] = pack2tr(e2, e3);                                         \
        }                                                                       \
        union { unsigned int u[4]; short8_t s; } pa, pb2;                       \
        pa.u[0]  = uu[0][0]; pa.u[1]  = uu[0][1]; pa.u[2]  = uu[1][0]; pa.u[3]  = uu[1][1]; \
        pb2.u[0] = uu[2][0]; pb2.u[1] = uu[2][1]; pb2.u[2] = uu[3][0]; pb2.u[3] = uu[3][1]; \
        lacc = __builtin_amdgcn_mfma_f32_16x16x32_bf16(ones, pa.s,  lacc, 0, 0, 0); \
        lacc = __builtin_amdgcn_mfma_f32_16x16x32_bf16(ones, pb2.s, lacc, 0, 0, 0); \
        short8_t vf00 = *(const short8_t*)(Vt + (VB_) * 2304 + l16 * 72 + quad * 8);        \
        short8_t vf01 = *(const short8_t*)(Vt + (VB_) * 2304 + l16 * 72 + 32 + quad * 8);   \
        short8_t vf10 = *(const short8_t*)(Vt + (VB_) * 2304 + (16 + l16) * 72 + quad * 8); \
        short8_t vf11 = *(const short8_t*)(Vt + (VB_) * 2304 + (16 + l16) * 72 + 32 + quad * 8); \
        od0 = __builtin_amdgcn_mfma_f32_16x16x32_bf16(vf00, pa.s,  od0, 0, 0, 0); \
        od0 = __builtin_amdgcn_mfma_f32_16x16x32_bf16(vf01, pb2.s, od0, 0, 0, 0); \
        od1 = __builtin_amdgcn_mfma_f32_16x16x32_bf16(vf10, pa.s,  od1, 0, 0, 0); \
        od1 = __builtin_amdgcn_mfma_f32_16x16x32_bf16(vf11, pb2.s, od1, 0, 0, 0); \
    } while (0)

#pragma unroll 2
    for (int s = 0; s < M_ / 64; s += 2) {
        const int tgt = s + 2 + half;
        short8_t nxt;
        if (tgt < M_ / 64) nxt = *(const short8_t*)gqv;

        STEPC((s) & 3, kqp);
        STEPC((s + 1) & 3, (kqp + 256));

        if (tgt < M_ / 64) {
            *(short8_t*)(vdst + (tgt & 3) * 2304) = nxt;
            gqv += 128;
        }
        kqp += 512;
        __syncthreads();
    }
#undef STEPC

    const float inv = 1.0f / lacc[0];

    unsigned short* ob = att_g + (size_t)(b * N_ + n0 + l16) * D_ + (bh & 7) * DH_;
    {
        unsigned int u0 = pack2rn(od0[0] * inv, od0[1] * inv);
        unsigned int u1 = pack2rn(od0[2] * inv, od0[3] * inv);
        *(uint2*)(ob + quad * 4) = make_uint2(u0, u1);
        unsigned int u2 = pack2rn(od1[0] * inv, od1[1] * inv);
        unsigned int u3 = pack2rn(od1[2] * inv, od1[3] * inv);
        *(uint2*)(ob + 16 + quad * 4) = make_uint2(u2, u3);
    }
}

// ---------------------------------------------------------------------------
// Fuse: out = att@Wf2.T + points@Wfc.T (bias folded), fp32 out.
// 64x64 tiles (512 blocks), unchanged from r8.
// ---------------------------------------------------------------------------
__global__ __launch_bounds__(256) void g_fuse3(
    const unsigned short* __restrict__ att_g,
    const float* __restrict__ points, const float* __restrict__ Wfc,
    const float* __restrict__ Wf,
    float* __restrict__ out)
{
    const int tid = threadIdx.x;
    const int wave = tid >> 6, lane = tid & 63, quad = lane >> 4, l16 = lane & 15;
    const int lbid = xcd_swz((int)blockIdx.x, (ROWS_ / 64) * 4);
    const int row0 = (lbid >> 2) * 64;
    const int col0 = (lbid & 3) * 64;

    __shared__ unsigned short Bs[64 * 256];  // 32 KB (Wf cols 256..511)

    stageB2<256, 64, 512>(Wf, col0, 256, Bs, tid);
    __syncthreads();

    float4_t acc[4];
#pragma unroll
    for (int c = 0; c < 4; c++) acc[c] = (float4_t){0.f, 0.f, 0.f, 0.f};

    const size_t arow = (size_t)(row0 + wave * 16 + l16) * D_;
#pragma unroll
    for (int k0 = 0; k0 < 256; k0 += 32) {
        short8_t af = *(const short8_t*)(att_g + arow + k0 + quad * 8);
#pragma unroll
        for (int c = 0; c < 4; c++)
            acc[c] = __builtin_amdgcn_mfma_f32_16x16x32_bf16(af, readB<256>(Bs, c, l16, quad, k0), acc[c], 0, 0, 0);
    }

    const int rbase = row0 + wave * 16 + quad * 4;
    float px[4], py[4], pz[4];
#pragma unroll
    for (int r = 0; r < 4; r++) {
        px[r] = points[(size_t)(rbase + r) * 3 + 0];
        py[r] = points[(size_t)(rbase + r) * 3 + 1];
        pz[r] = points[(size_t)(rbase + r) * 3 + 2];
    }
#pragma unroll
    for (int c = 0; c < 4; c++) {
        int col = col0 + 16 * c + l16;
        float4 wf = *(const float4*)(Wfc + (size_t)col * 4);
#pragma unroll
        for (int r = 0; r < 4; r++) {
            out[(size_t)(rbase + r) * D_ + col] =
                acc[c][r] + px[r] * wf.x + py[r] * wf.y + pz[r] * wf.z + wf.w;
        }
    }
}

// ---------------------------------------------------------------------------
extern "C" void kernel_launch(void* const* d_in, const int* in_sizes, int n_in,
                              void* d_out, int out_size, void* d_ws, size_t ws_size,
                              hipStream_t stream)
{
    const float* points = (const float*)d_in[0];
    const float* voxel  = (const float*)d_in[1];
    const float* Wp  = (const float*)d_in[2];
    const float* bp  = (const float*)d_in[3];
    const float* Wq  = (const float*)d_in[4];
    const float* bq  = (const float*)d_in[5];
    const float* Wk  = (const float*)d_in[6];
    const float* bk  = (const float*)d_in[7];
    const float* Wv  = (const float*)d_in[8];
    const float* bv  = (const float*)d_in[9];
    const float* Wf  = (const float*)d_in[10];
    const float* bfb = (const float*)d_in[11];
    float* out = (float*)d_out;

    float* Wfc = (float*)d_ws;                             // [256][4] f32
    unsigned short* kq_g  = (unsigned short*)(Wfc + 256 * 4);  // [b][h][m][4] bf16
    unsigned short* vt_g  = kq_g + (size_t)B_ * H_ * M_ * 4;   // [b][h][dh][m]
    unsigned short* att_g = vt_g + (size_t)KVROWS_ * D_;

    g_projkv5<<<dim3(513), dim3(256), 0, stream>>>(voxel, Wp, bp, Wq, bq, Wk, bk,
                                                   Wv, bv, Wf, bfb, kq_g, vt_g, Wfc);
    k_attn12<<<dim3(512), dim3(512), 0, stream>>>(points, kq_g, vt_g, att_g);
    g_fuse3 <<<dim3((ROWS_ / 64) * 4), dim3(256), 0, stream>>>(att_g, points, Wfc, Wf, out);
}

// Round 10
// 144.651 us; speedup vs baseline: 1.0061x; 1.0061x over previous
//
#include <hip/hip_runtime.h>

#define B_ 2
#define N_ 4096
#define M_ 2048
#define D_ 256
#define H_ 8
#define DH_ 32
#define ROWS_ (B_*N_)
#define KVROWS_ (B_*M_)
#define ODHALF_ ((size_t)ROWS_*D_)     // floats per od half-buffer
#define LHALF_ ((size_t)B_*H_*N_)      // floats per l half-buffer
// SCALE * log2(e): q pre-scaled so softmax = exp2
#define PRE_ (0.17677669529663687f * 1.4426950408889634f)
#define CBASE_ 32.0f

typedef __attribute__((ext_vector_type(8))) short short8_t;
typedef __attribute__((ext_vector_type(4))) float float4_t;

#if defined(__has_builtin)
# if __has_builtin(__builtin_amdgcn_exp2f)
#  define EXP2F(x) __builtin_amdgcn_exp2f(x)
# else
#  define EXP2F(x) exp2f(x)
# endif
#else
# define EXP2F(x) exp2f(x)
#endif

// RTNE round-to-bf16 helper: rounded 32-bit word (bf16 in high half)
__device__ __forceinline__ unsigned int rne_u(float f) {
    union { float f; unsigned int u; } c;
    c.f = f;
    return c.u + 0x7FFFu + ((c.u >> 16) & 1u);
}

__device__ __forceinline__ unsigned short f2us(float f) {
    return (unsigned short)(rne_u(f) >> 16);
}

// pack two RTNE bf16: low16 = a, high16 = b  (single v_perm_b32 combine)
__device__ __forceinline__ unsigned int pack2rn(float a, float b) {
    return __builtin_amdgcn_perm(rne_u(b), rne_u(a), 0x07060302u);
}

// truncation pack (P tiles only; <=2^-8 rel err) — single v_perm_b32
__device__ __forceinline__ unsigned int pack2tr(float a, float b) {
    union { float f; unsigned int u; } x, y;
    x.f = a; y.f = b;
    return __builtin_amdgcn_perm(y.u, x.u, 0x07060302u);
}

__device__ __forceinline__ short8_t cvt8(float4 a, float4 b) {
    union { unsigned int u[4]; short8_t s; } c;
    c.u[0] = pack2rn(a.x, a.y);
    c.u[1] = pack2rn(a.z, a.w);
    c.u[2] = pack2rn(b.x, b.y);
    c.u[3] = pack2rn(b.z, b.w);
    return c.s;
}

// bijective XCD-aware block-id swizzle (valid when nwg % 8 == 0)
__device__ __forceinline__ int xcd_swz(int bid, int nwg) {
    const int cpx = nwg >> 3;
    return (bid & 7) * cpx + (bid >> 3);
}

// ---------------------------------------------------------------------------
// Stage NCOL x K fp32 weight block (source row stride LDSRC, col offset kof)
// into XOR-swizzled bf16 LDS.
// ---------------------------------------------------------------------------
template<int K, int NCOL, int LDSRC>
__device__ __forceinline__ void stageB2(const float* __restrict__ W, int col0, int kof,
                                        unsigned short* __restrict__ Bs, int tid)
{
    const int n = tid & (NCOL - 1), g = tid / NCOL;
    const int GROUPS = 256 / NCOL;
    const int CPT = (K / 8) / GROUPS;
    const float* src = W + (size_t)(col0 + n) * LDSRC + kof + g * (K / GROUPS);
#pragma unroll
    for (int ci = 0; ci < CPT; ci++) {
        int logc = g * CPT + ci;
        int phys = logc ^ (n & 7);
        short8_t v = cvt8(*(const float4*)(src + ci * 8), *(const float4*)(src + ci * 8 + 4));
        *(short8_t*)(Bs + (size_t)n * K + phys * 8) = v;
    }
}

template<int K>
__device__ __forceinline__ short8_t readB(const unsigned short* __restrict__ Bs,
                                          int c, int l16, int quad, int k0)
{
    int phys = ((k0 >> 3) + quad) ^ (l16 & 7);
    return *(const short8_t*)(Bs + (size_t)(16 * c + l16) * K + phys * 8);
}

// ---------------------------------------------------------------------------
// KV projection + weight-fold prep (r8 shape, verbatim).
// ---------------------------------------------------------------------------
__global__ __launch_bounds__(256) void g_projkv4(
    const float* __restrict__ voxel,
    const float* __restrict__ Wp, const float* __restrict__ bp,
    const float* __restrict__ Wq, const float* __restrict__ bq,
    const float* __restrict__ Wk, const float* __restrict__ bk,
    const float* __restrict__ Wv, const float* __restrict__ bv,
    const float* __restrict__ Wf, const float* __restrict__ bfb,
    unsigned short* __restrict__ k_g, unsigned short* __restrict__ vt_g,
    float* __restrict__ Wqc, float* __restrict__ Wfc)
{
    const int tid = threadIdx.x;
    const int wave = tid >> 6, lane = tid & 63, quad = lane >> 4, l16 = lane & 15;

    __shared__ unsigned short Bs[64 * 256];   // 32 KB

    const int bid = (int)blockIdx.x;
    if (bid < 512) {
        const int lbid = xcd_swz(bid, 512);
        const int row0 = (lbid >> 3) * 64;
        const int sub  = lbid & 7;
        const int col0 = (sub >> 1) * 64;
        const bool isV = sub & 1;

        stageB2<256, 64, 256>(isV ? Wv : Wk, col0, 0, Bs, tid);

        const float* arow = voxel + (size_t)(row0 + wave * 16 + l16) * D_;
        short8_t af[8];
#pragma unroll
        for (int i = 0; i < 8; i++)
            af[i] = cvt8(*(const float4*)(arow + i * 32 + quad * 8),
                         *(const float4*)(arow + i * 32 + quad * 8 + 4));

        float4_t acc[4];
#pragma unroll
        for (int c = 0; c < 4; c++) acc[c] = (float4_t){0.f, 0.f, 0.f, 0.f};
        __syncthreads();
#pragma unroll
        for (int i = 0; i < 8; i++)
#pragma unroll
            for (int c = 0; c < 4; c++)
                acc[c] = __builtin_amdgcn_mfma_f32_16x16x32_bf16(af[i], readB<256>(Bs, c, l16, quad, i * 32), acc[c], 0, 0, 0);

        if (!isV) {
#pragma unroll
            for (int c = 0; c < 4; c++) {
                int col = col0 + 16 * c + l16;
                float bbk = bk[col];
#pragma unroll
                for (int r = 0; r < 4; r++) {
                    int row = row0 + wave * 16 + quad * 4 + r;
                    k_g[(size_t)row * D_ + col] = f2us(acc[c][r] + bbk);
                }
            }
        } else {
            const int b = row0 / M_;
            const int m0 = row0 - b * M_ + wave * 16 + quad * 4;
#pragma unroll
            for (int c = 0; c < 4; c++) {
                int col = col0 + 16 * c + l16;
                float bbv = bv[col];
                int h = col >> 5, dh = col & 31;
                unsigned int u0 = pack2rn(acc[c][0] + bbv, acc[c][1] + bbv);
                unsigned int u1 = pack2rn(acc[c][2] + bbv, acc[c][3] + bbv);
                *(uint2*)(vt_g + (size_t)((b * H_ + h) * DH_ + dh) * M_ + m0) = make_uint2(u0, u1);
            }
        }
    } else {
        // ---- prep role: fold fan-in-3 weights in f32 (exact) ----
        const int role = bid - 512;               // 0: Wqc, 1: Wfc
        float* wps = (float*)Bs;                  // [256][4] staged Wp|bp
        *(float4*)(wps + tid * 4) = make_float4(Wp[tid * 3 + 0], Wp[tid * 3 + 1],
                                                Wp[tid * 3 + 2], bp[tid]);
        __syncthreads();
        const int col = tid;
        const float* wrow = role ? (Wf + (size_t)col * 512) : (Wq + (size_t)col * 256);
        float a0 = 0.f, a1 = 0.f, a2 = 0.f, ab = 0.f;
#pragma unroll 4
        for (int d = 0; d < 256; d += 4) {
            float4 wv = *(const float4*)(wrow + d);
            float4 w0 = *(const float4*)(wps + (d + 0) * 4);
            float4 w1 = *(const float4*)(wps + (d + 1) * 4);
            float4 w2 = *(const float4*)(wps + (d + 2) * 4);
            float4 w3 = *(const float4*)(wps + (d + 3) * 4);
            a0 += wv.x * w0.x + wv.y * w1.x + wv.z * w2.x + wv.w * w3.x;
            a1 += wv.x * w0.y + wv.y * w1.y + wv.z * w2.y + wv.w * w3.y;
            a2 += wv.x * w0.z + wv.y * w1.z + wv.z * w2.z + wv.w * w3.z;
            ab += wv.x * w0.w + wv.y * w1.w + wv.z * w2.w + wv.w * w3.w;
        }
        if (role == 0) {
            *(float4*)(Wqc + (size_t)col * 4) =
                make_float4(a0 * PRE_, a1 * PRE_, a2 * PRE_, (ab + bq[col]) * PRE_);
        } else {
            *(float4*)(Wfc + (size_t)col * 4) =
                make_float4(a0, a1, a2, ab + bfb[col]);
        }
    }
}

// ---------------------------------------------------------------------------
// MFMA flash attention v13 = r8's v11 with M-SPLIT (no max-tracking softmax
// -> partials combine by addition). Grid 1024: each block does HALF the KV
// range (16 steps), writes raw od (f32) and l partials; fuse combines.
// Per-wave inner loop bit-identical to r8. 4 blocks/CU by LDS (38 KB);
// plain launch_bounds(512) — no min-waves clamp (r9 lesson: forced caps
// spill the STEPC state to scratch).
// ---------------------------------------------------------------------------
__global__ __launch_bounds__(512) void k_attn13(
    const float* __restrict__ points, const float* __restrict__ Wqc,
    const unsigned short* __restrict__ k_g,
    const unsigned short* __restrict__ vt_g,
    float* __restrict__ od_g, float* __restrict__ l_g)
{
    const int tid = threadIdx.x;
    const int w = tid >> 6, lane = tid & 63, quad = lane >> 4, l16 = lane & 15;
    const int lbid = xcd_swz((int)blockIdx.x, B_ * H_ * (N_ / 128) * 2);
    const int mh = lbid & 1;              // M half
    const int nt = (lbid >> 1) & 31;      // N/128
    const int bh = lbid >> 6;             // b*8+h
    const int b = bh >> 3, h = bh & 7;
    const int n0 = nt * 128 + w * 16;

    __shared__ unsigned short Kt[4][64][40];   // 20 KB
    __shared__ unsigned short Vt[4][32][72];   // 18 KB

    const unsigned short* kbase = k_g + ((size_t)b * M_ + mh * (M_ / 2)) * D_ + h * DH_;
    const unsigned short* vbase = vt_g + (size_t)bh * DH_ * M_ + mh * (M_ / 2);

    // staging role: one 16B chunk per thread per step
    const bool isK = (tid < 256);
    const int kr = tid >> 2, kc = tid & 3;            // K: 64 rows x 4 chunks
    const int vr = (tid - 256) >> 3, vc = tid & 7;    // V: 32 rows x 8 chunks
    const int ksr = kr ^ ((kr & 8) >> 1);             // rho-permuted K LDS row

    const int gstep = isK ? 64 * D_ : 64;
    const unsigned short* gq = isK ? (kbase + (size_t)kr * D_ + kc * 8)
                                   : (vbase + (size_t)vr * M_ + vc * 8);
    unsigned short* ldst = isK ? (&Kt[0][0][0] + ksr * 40 + kc * 8)
                               : (&Vt[0][0][0] + vr * 72 + vc * 8);
    const int lstride = isK ? 2560 : 2304;            // buf stride in shorts

    // prologue: stage steps 0,1 into bufs 0,1
    *(short8_t*)ldst = *(const short8_t*)gq;
    gq += gstep;
    *(short8_t*)(ldst + lstride) = *(const short8_t*)gq;

    // permuted K-row read indices (rho applied; XOR safe: bit2 never carries)
    const int rbas = 8 * (l16 >> 2) + (l16 & 3);
    const int rx = l16 & 4;
    int krow[4];
#pragma unroll
    for (int t = 0; t < 4; t++)
        krow[t] = (rbas + 4 * (t & 1) + 32 * (t >> 1)) ^ rx;

    // q inline: row = b*N_ + n0 + l16, cols h*32 + quad*8 + j  (f32-exact)
    const size_t qrow = (size_t)(b * N_ + n0 + l16);
    const float p0 = points[qrow * 3 + 0];
    const float p1 = points[qrow * 3 + 1];
    const float p2 = points[qrow * 3 + 2];
    float q8[8];
#pragma unroll
    for (int j = 0; j < 8; j++) {
        float4 wc = *(const float4*)(Wqc + (size_t)(h * DH_ + quad * 8 + j) * 4);
        q8[j] = p0 * wc.x + p1 * wc.y + p2 * wc.z + wc.w;
    }
    short8_t qf = cvt8(make_float4(q8[0], q8[1], q8[2], q8[3]),
                       make_float4(q8[4], q8[5], q8[6], q8[7]));

    // all-ones bf16 A-fragment for the l-sum MFMA
    short8_t ones;
#pragma unroll
    for (int j = 0; j < 8; j++) ones[j] = (short)0x3F80;

    float4_t od0 = {0.f, 0.f, 0.f, 0.f};
    float4_t od1 = {0.f, 0.f, 0.f, 0.f};
    float4_t lacc = {0.f, 0.f, 0.f, 0.f};

    const float4_t zc = {-CBASE_, -CBASE_, -CBASE_, -CBASE_};

    __syncthreads();

#define STEPC(KB_, VB_)                                                         \
    do {                                                                        \
        float4_t st[4];                                                         \
        _Pragma("unroll")                                                       \
        for (int t = 0; t < 4; t++) {                                           \
            short8_t kf = *(const short8_t*)&Kt[KB_][krow[t]][quad * 8];        \
            st[t] = __builtin_amdgcn_mfma_f32_16x16x32_bf16(kf, qf, zc, 0, 0, 0); \
        }                                                                       \
        unsigned int uu[4][2];                                                  \
        _Pragma("unroll")                                                       \
        for (int t = 0; t < 4; t++) {                                           \
            float e0 = EXP2F(st[t][0]);                                         \
            float e1 = EXP2F(st[t][1]);                                         \
            float e2 = EXP2F(st[t][2]);                                         \
            float e3 = EXP2F(st[t][3]);                                         \
            uu[t][0] = pack2tr(e0, e1);                                         \
            uu[t][1] = pack2tr(e2, e3);                                         \
        }                                                                       \
        union { unsigned int u[4]; short8_t s; } pa, pb2;                       \
        pa.u[0]  = uu[0][0]; pa.u[1]  = uu[0][1];                               \
        pa.u[2]  = uu[1][0]; pa.u[3]  = uu[1][1];                               \
        pb2.u[0] = uu[2][0]; pb2.u[1] = uu[2][1];                               \
        pb2.u[2] = uu[3][0]; pb2.u[3] = uu[3][1];                               \
        lacc = __builtin_amdgcn_mfma_f32_16x16x32_bf16(ones, pa.s,  lacc, 0, 0, 0); \
        lacc = __builtin_amdgcn_mfma_f32_16x16x32_bf16(ones, pb2.s, lacc, 0, 0, 0); \
        short8_t vf00 = *(const short8_t*)&Vt[VB_][l16][quad * 8];              \
        short8_t vf01 = *(const short8_t*)&Vt[VB_][l16][32 + quad * 8];         \
        short8_t vf10 = *(const short8_t*)&Vt[VB_][16 + l16][quad * 8];         \
        short8_t vf11 = *(const short8_t*)&Vt[VB_][16 + l16][32 + quad * 8];    \
        od0 = __builtin_amdgcn_mfma_f32_16x16x32_bf16(vf00, pa.s,  od0, 0, 0, 0); \
        od0 = __builtin_amdgcn_mfma_f32_16x16x32_bf16(vf01, pb2.s, od0, 0, 0, 0); \
        od1 = __builtin_amdgcn_mfma_f32_16x16x32_bf16(vf10, pa.s,  od1, 0, 0, 0); \
        od1 = __builtin_amdgcn_mfma_f32_16x16x32_bf16(vf11, pb2.s, od1, 0, 0, 0); \
    } while (0)

#pragma unroll 2
    for (int s = 0; s < M_ / 128; s += 2) {      // 16 steps (half of M)
        const bool m0 = (s + 2 < M_ / 128);
        const bool m1 = (s + 3 < M_ / 128);
        short8_t nxt0, nxt1;
        if (m0) { gq += gstep; nxt0 = *(const short8_t*)gq; }
        if (m1) { gq += gstep; nxt1 = *(const short8_t*)gq; }

        STEPC((s) & 3, (s) & 3);
        STEPC((s + 1) & 3, (s + 1) & 3);

        if (m0) *(short8_t*)(ldst + ((s + 2) & 3) * lstride) = nxt0;
        if (m1) *(short8_t*)(ldst + ((s + 3) & 3) * lstride) = nxt1;
        __syncthreads();
    }
#undef STEPC

    // epilogue: raw f32 partials (combined in fuse)
    float* obf = od_g + (size_t)mh * ODHALF_ + (size_t)(b * N_ + n0 + l16) * D_ + h * DH_;
    *(float4_t*)(obf + quad * 4) = od0;
    *(float4_t*)(obf + 16 + quad * 4) = od1;
    if (quad == 0)
        l_g[(size_t)mh * LHALF_ + (size_t)bh * N_ + n0 + l16] = lacc[0];
}

// ---------------------------------------------------------------------------
// Fuse v4: out = ((od0+od1)/(l0+l1)) @ Wf2.T + points@Wfc.T (bias folded).
// A-fragments built from f32 od partials (combine + normalize + bf16 pack
// inline). 64x64 tiles (512 blocks).
// ---------------------------------------------------------------------------
__global__ __launch_bounds__(256) void g_fuse4(
    const float* __restrict__ od_g, const float* __restrict__ l_g,
    const float* __restrict__ points, const float* __restrict__ Wfc,
    const float* __restrict__ Wf,
    float* __restrict__ out)
{
    const int tid = threadIdx.x;
    const int wave = tid >> 6, lane = tid & 63, quad = lane >> 4, l16 = lane & 15;
    const int lbid = xcd_swz((int)blockIdx.x, (ROWS_ / 64) * 4);
    const int row0 = (lbid >> 2) * 64;
    const int col0 = (lbid & 3) * 64;

    __shared__ unsigned short Bs[64 * 256];  // 32 KB (Wf cols 256..511)

    stageB2<256, 64, 512>(Wf, col0, 256, Bs, tid);

    // per-head inverse denominators for this lane's A row
    const int rowA = row0 + wave * 16 + l16;
    const int bA = rowA >> 12, nA = rowA & (N_ - 1);
    float inv[8];
#pragma unroll
    for (int hh = 0; hh < 8; hh++) {
        size_t li = (size_t)(bA * H_ + hh) * N_ + nA;
        inv[hh] = 1.0f / (l_g[li] + l_g[li + LHALF_]);
    }

    __syncthreads();

    float4_t acc[4];
#pragma unroll
    for (int c = 0; c < 4; c++) acc[c] = (float4_t){0.f, 0.f, 0.f, 0.f};

    const size_t odrow = (size_t)rowA * D_;
#pragma unroll
    for (int k0 = 0; k0 < 256; k0 += 32) {
        const float iv = inv[k0 >> 5];
        const float* pa = od_g + odrow + k0 + quad * 8;
        float4 a0 = *(const float4*)(pa);
        float4 a1 = *(const float4*)(pa + 4);
        float4 c0 = *(const float4*)(pa + ODHALF_);
        float4 c1 = *(const float4*)(pa + ODHALF_ + 4);
        short8_t af = cvt8(
            make_float4((a0.x + c0.x) * iv, (a0.y + c0.y) * iv,
                        (a0.z + c0.z) * iv, (a0.w + c0.w) * iv),
            make_float4((a1.x + c1.x) * iv, (a1.y + c1.y) * iv,
                        (a1.z + c1.z) * iv, (a1.w + c1.w) * iv));
#pragma unroll
        for (int c = 0; c < 4; c++)
            acc[c] = __builtin_amdgcn_mfma_f32_16x16x32_bf16(af, readB<256>(Bs, c, l16, quad, k0), acc[c], 0, 0, 0);
    }

    const int rbase = row0 + wave * 16 + quad * 4;
    float px[4], py[4], pz[4];
#pragma unroll
    for (int r = 0; r < 4; r++) {
        px[r] = points[(size_t)(rbase + r) * 3 + 0];
        py[r] = points[(size_t)(rbase + r) * 3 + 1];
        pz[r] = points[(size_t)(rbase + r) * 3 + 2];
    }
#pragma unroll
    for (int c = 0; c < 4; c++) {
        int col = col0 + 16 * c + l16;
        float4 wf = *(const float4*)(Wfc + (size_t)col * 4);
#pragma unroll
        for (int r = 0; r < 4; r++) {
            out[(size_t)(rbase + r) * D_ + col] =
                acc[c][r] + px[r] * wf.x + py[r] * wf.y + pz[r] * wf.z + wf.w;
        }
    }
}

// ---------------------------------------------------------------------------
extern "C" void kernel_launch(void* const* d_in, const int* in_sizes, int n_in,
                              void* d_out, int out_size, void* d_ws, size_t ws_size,
                              hipStream_t stream)
{
    const float* points = (const float*)d_in[0];
    const float* voxel  = (const float*)d_in[1];
    const float* Wp  = (const float*)d_in[2];
    const float* bp  = (const float*)d_in[3];
    const float* Wq  = (const float*)d_in[4];
    const float* bq  = (const float*)d_in[5];
    const float* Wk  = (const float*)d_in[6];
    const float* bk  = (const float*)d_in[7];
    const float* Wv  = (const float*)d_in[8];
    const float* bv  = (const float*)d_in[9];
    const float* Wf  = (const float*)d_in[10];
    const float* bfb = (const float*)d_in[11];
    float* out = (float*)d_out;

    float* Wqc = (float*)d_ws;                         // [256][4] f32
    float* Wfc = Wqc + 256 * 4;                        // [256][4] f32
    unsigned short* k_g   = (unsigned short*)(Wfc + 256 * 4);
    unsigned short* vt_g  = k_g  + (size_t)KVROWS_ * D_;   // [b][h][dh][m]
    float* od_g = (float*)(vt_g + (size_t)KVROWS_ * D_);   // 2 x [b][n][256] f32
    float* l_g  = od_g + 2 * ODHALF_;                      // 2 x [b][h][n] f32

    g_projkv4<<<dim3(514), dim3(256), 0, stream>>>(voxel, Wp, bp, Wq, bq, Wk, bk,
                                                   Wv, bv, Wf, bfb, k_g, vt_g, Wqc, Wfc);
    k_attn13<<<dim3(B_ * H_ * (N_ / 128) * 2), dim3(512), 0, stream>>>(points, Wqc, k_g, vt_g, od_g, l_g);
    g_fuse4 <<<dim3((ROWS_ / 64) * 4), dim3(256), 0, stream>>>(od_g, l_g, points, Wfc, Wf, out);
}